// Round 5
// baseline (480.097 us; speedup 1.0000x reference)
//
#include <hip/hip_runtime.h>

// Dims: x,x1,x2:(8,512,32,32) fp32; w1:(256,512,1,1); b1:(256); w2:(512,256,3,3);
// b2:(512); gamma,bn_bias:(512); beta:(1). Out:(8,512,32,32) fp32.
// G = 16 images (8 from x1 -> group0, 8 from x2 -> group1), N = 1024 spatial.
//
// ws layout (float offsets), total 13,772,800 fl = 55.09 MB:
//  [0        : 8388608 ) RF : x12t hi/lo -> F=yhat hi/lo (conv2 out) -> xt hi/lo
//  [8388608  : 12582912) RY : Y1t hi/lo (conv1 out) -> S0 + S1 partial; att in S0
//  [12582912 : 13762560) w2b hi/lo  [tap][co][ci]
//  [13762560 : 13764608) stats (sum, sumsq per group x 512)
//  [13764608 : 13772800) rowsum [16][512]

typedef __attribute__((ext_vector_type(8))) short bfrag;    // 8 bf16 = 4 VGPR
typedef __attribute__((ext_vector_type(4))) float facc;     // 4 fp32 acc
typedef __attribute__((ext_vector_type(16))) float facc16;  // 16 fp32 acc (32x32)

__device__ __forceinline__ unsigned short bf16_rn(float v) {
  unsigned u = __float_as_uint(v);
  return (unsigned short)((u + 0x7fffu + ((u >> 16) & 1u)) >> 16);
}

// w2 [co512][ci256][tap9] fp32 -> w2bhi/lo [tap][co][ci] bf16 (hi/lo split).
// Also zeroes stats+rowsum (10240 floats) from blocks 0..39.
__global__ __launch_bounds__(256) void prep_w2(const float* __restrict__ w2,
                                               unsigned short* __restrict__ hi,
                                               unsigned short* __restrict__ lo,
                                               float* __restrict__ statsz) {
  if (blockIdx.x < 40) statsz[blockIdx.x * 256 + threadIdx.x] = 0.f;
  int co = blockIdx.x;
  int ci = threadIdx.x;
  const float* src = w2 + ((size_t)co * 256 + ci) * 9;
#pragma unroll
  for (int tap = 0; tap < 9; tap++) {
    float v = src[tap];
    unsigned short h = bf16_rn(v);
    float fh = __uint_as_float((unsigned)h << 16);
    unsigned short l = bf16_rn(v - fh);
    size_t idx = ((size_t)tap * 512 + co) * 256 + ci;
    hi[idx] = h;
    lo[idx] = l;
  }
}

// fp32 [z][512 ci][1024 px] -> [z][px][512 ci] bf16 hi/lo. z<8: src0, z>=8: src1.
__global__ __launch_bounds__(256) void transpose_split(
    const float* __restrict__ src0, const float* __restrict__ src1,
    unsigned short* __restrict__ hi, unsigned short* __restrict__ lo) {
  __shared__ float tile[32][33];
  int z = blockIdx.z;
  const float* src = (z < 8) ? src0 + (size_t)z * 524288 : src1 + (size_t)(z - 8) * 524288;
  int ci0 = blockIdx.y * 32, p0 = blockIdx.x * 32;
  int t = threadIdx.x;
  {
    int ci_l = t >> 5, p_l = t & 31;
#pragma unroll
    for (int j = 0; j < 4; j++)
      tile[ci_l + 8 * j][p_l] = src[(size_t)(ci0 + ci_l + 8 * j) * 1024 + p0 + p_l];
  }
  __syncthreads();
  {
    int p_l = t >> 3, cg = (t & 7) * 4;
    unsigned short hh[4], ll[4];
#pragma unroll
    for (int j = 0; j < 4; j++) {
      float v = tile[cg + j][p_l];
      hh[j] = bf16_rn(v);
      ll[j] = bf16_rn(v - __uint_as_float((unsigned)hh[j] << 16));
    }
    size_t idx = ((size_t)z * 1024 + p0 + p_l) * 512 + ci0 + cg;
    *(ushort4*)(hi + idx) = make_ushort4(hh[0], hh[1], hh[2], hh[3]);
    *(ushort4*)(lo + idx) = make_ushort4(ll[0], ll[1], ll[2], ll[3]);
  }
}

// Split-bf16 3-pass NT MFMA GEMM: D[m][n] = sum_k A[m][k]*B[n][k].
// Block 128x128, 4 waves 2x2, wave = 4x4 tiles of 16x16x32, K-step 64.
// AF32=1: A is fp32 (w1), split in-register during staging.
// KSPLIT=1: blockIdx.z = kh*8 + zb; EPI1 writes partial S to S + kh*2097152,
//           affine terms only when kh==0.
// EPI 0: +bias[m], emit bf16 hi/lo transposed [z][n][m] (conv1 -> Y1t)
// EPI 1: BN-folded scores epilogue -> S fp32 [z][m][n]
// EPI 2: fp32 store out[z][m][n] * p0[0]
template <int KTOT, int EPI, int AF32, int KSPLIT>
__global__ __launch_bounds__(256, 2) void gemm_nt(
    const void* __restrict__ Ahi_, const unsigned short* __restrict__ Alo,
    int aLD, long long aBS,
    const unsigned short* __restrict__ Bhi, const unsigned short* __restrict__ Blo,
    int bLD, long long bBS,
    void* __restrict__ out0, void* __restrict__ out1,
    const float* __restrict__ p0, const float* __restrict__ p1,
    const float* __restrict__ p2, const float* __restrict__ p3) {
  __shared__ __attribute__((aligned(16))) unsigned char smem[65536];
  int t = threadIdx.x;
  int z = blockIdx.z;
  int zb = z, kh = 0;
  if (KSPLIT) { zb = z & 7; kh = z >> 3; }
  int m0 = blockIdx.y * 128, n0 = blockIdx.x * 128;
  int w = t >> 6, lane = t & 63;
  int lm = lane & 15, q = lane >> 4;
  int mh = (w & 1) * 64, nh = (w >> 1) * 64;
  facc acc[4][4] = {};  // [mt][nt]
  for (int k0 = 0; k0 < KTOT; k0 += 64) {
    __syncthreads();
    if (AF32) {
      const float* Af = (const float*)Ahi_ + (size_t)zb * aBS;
#pragma unroll
      for (int j = 0; j < 8; j++) {
        int idx = t + 256 * j;
        int row = idx >> 4, c4 = idx & 15;
        float4 v = *(const float4*)(Af + (size_t)(m0 + row) * aLD + k0 + c4 * 4);
        unsigned short h0 = bf16_rn(v.x), h1 = bf16_rn(v.y), h2 = bf16_rn(v.z), h3 = bf16_rn(v.w);
        unsigned short l0 = bf16_rn(v.x - __uint_as_float((unsigned)h0 << 16));
        unsigned short l1 = bf16_rn(v.y - __uint_as_float((unsigned)h1 << 16));
        unsigned short l2 = bf16_rn(v.z - __uint_as_float((unsigned)h2 << 16));
        unsigned short l3 = bf16_rn(v.w - __uint_as_float((unsigned)h3 << 16));
        int base = row * 256 + (((c4 >> 1) ^ (row & 7)) * 16) + (c4 & 1) * 8;
        *(ushort4*)(smem + base) = make_ushort4(h0, h1, h2, h3);
        *(ushort4*)(smem + base + 128) = make_ushort4(l0, l1, l2, l3);
      }
    } else {
      const unsigned short* Ah = (const unsigned short*)Ahi_ + (size_t)zb * aBS + kh * KTOT;
      const unsigned short* Al = Alo + (size_t)zb * aBS + kh * KTOT;
#pragma unroll
      for (int j = 0; j < 8; j++) {
        int idx = t + 256 * j;
        int row = idx >> 4, c = idx & 15;
        const unsigned short* src = (c < 8) ? Ah : Al;
        uint4 v = *(const uint4*)(src + (size_t)(m0 + row) * aLD + k0 + (c & 7) * 8);
        *(uint4*)(smem + row * 256 + ((((c & 7) ^ (row & 7)) | (c & 8)) * 16)) = v;
      }
    }
#pragma unroll
    for (int j = 0; j < 8; j++) {
      int idx = t + 256 * j;
      int row = idx >> 4, c = idx & 15;
      const unsigned short* src = (c < 8) ? Bhi : Blo;
      uint4 v = *(const uint4*)(src + (size_t)zb * bBS + (size_t)kh * KTOT +
                                (size_t)(n0 + row) * bLD + k0 + (c & 7) * 8);
      *(uint4*)(smem + 32768 + row * 256 + ((((c & 7) ^ (row & 7)) | (c & 8)) * 16)) = v;
    }
    __syncthreads();
#pragma unroll
    for (int ks = 0; ks < 2; ks++) {
      bfrag ah[4], al[4], bh[4], bl[4];
#pragma unroll
      for (int mt = 0; mt < 4; mt++) {
        int m = mh + mt * 16 + lm;
        int phys = ((ks * 4 + q) ^ (m & 7)) * 16;
        const unsigned char* p = smem + m * 256;
        ah[mt] = *(const bfrag*)(p + phys);
        al[mt] = *(const bfrag*)(p + phys + 128);
      }
#pragma unroll
      for (int nt = 0; nt < 4; nt++) {
        int n = nh + nt * 16 + lm;
        int phys = ((ks * 4 + q) ^ (n & 7)) * 16;
        const unsigned char* p = smem + 32768 + n * 256;
        bh[nt] = *(const bfrag*)(p + phys);
        bl[nt] = *(const bfrag*)(p + phys + 128);
      }
#pragma unroll
      for (int mt = 0; mt < 4; mt++)
#pragma unroll
        for (int nt = 0; nt < 4; nt++) {
          acc[mt][nt] = __builtin_amdgcn_mfma_f32_16x16x32_bf16(ah[mt], bh[nt], acc[mt][nt], 0, 0, 0);
          acc[mt][nt] = __builtin_amdgcn_mfma_f32_16x16x32_bf16(ah[mt], bl[nt], acc[mt][nt], 0, 0, 0);
          acc[mt][nt] = __builtin_amdgcn_mfma_f32_16x16x32_bf16(al[mt], bh[nt], acc[mt][nt], 0, 0, 0);
        }
    }
  }
  if (EPI == 0) {
    unsigned short* Oh = (unsigned short*)out0;
    unsigned short* Ol = (unsigned short*)out1;
#pragma unroll
    for (int mt = 0; mt < 4; mt++) {
      int mb = m0 + mh + mt * 16 + q * 4;
#pragma unroll
      for (int nt = 0; nt < 4; nt++) {
        int n = n0 + nh + nt * 16 + lm;
        unsigned short hh[4], ll[4];
#pragma unroll
        for (int r = 0; r < 4; r++) {
          float v = acc[mt][nt][r] + p0[mb + r];
          hh[r] = bf16_rn(v);
          ll[r] = bf16_rn(v - __uint_as_float((unsigned)hh[r] << 16));
        }
        size_t o = ((size_t)(zb * 1024 + n)) * 256 + mb;
        *(ushort4*)(Oh + o) = make_ushort4(hh[0], hh[1], hh[2], hh[3]);
        *(ushort4*)(Ol + o) = make_ushort4(ll[0], ll[1], ll[2], ll[3]);
      }
    }
  } else if (EPI == 1) {
    // S = a1*a2*G (+ kh==0: a1*t2*r1 + t1*a2*r2 + 1024*t1*t2)
    float* S = (float*)out0 + (size_t)kh * 2097152;
    const float* stats = p0;
    const float* rowsum = p1;
    const float* gamma = p2;
    const float* bnb = p3;
    float a2v[4], t2v[4], r2v[4];
#pragma unroll
    for (int nt = 0; nt < 4; nt++) {
      int d = n0 + nh + nt * 16 + lm;
      float mu = stats[512 + d] * (1.f / 8192.f);
      float var = stats[1536 + d] * (1.f / 8192.f) - mu * mu;
      float a = gamma[d] * rsqrtf(var + 1e-5f);
      a2v[nt] = a;
      t2v[nt] = bnb[d] - mu * a;
      r2v[nt] = rowsum[(8 + zb) * 512 + d];
    }
#pragma unroll
    for (int mt = 0; mt < 4; mt++)
#pragma unroll
      for (int r = 0; r < 4; r++) {
        int cc = m0 + mh + mt * 16 + q * 4 + r;
        float mu = stats[cc] * (1.f / 8192.f);
        float var = stats[1024 + cc] * (1.f / 8192.f) - mu * mu;
        float a1 = gamma[cc] * rsqrtf(var + 1e-5f);
        float t1 = bnb[cc] - mu * a1;
        float r1 = rowsum[zb * 512 + cc];
#pragma unroll
        for (int nt = 0; nt < 4; nt++) {
          int d = n0 + nh + nt * 16 + lm;
          float sc = a1 * a2v[nt] * acc[mt][nt][r];
          if (kh == 0)
            sc += a1 * t2v[nt] * r1 + t1 * a2v[nt] * r2v[nt] + 1024.f * t1 * t2v[nt];
          S[((size_t)(zb * 512 + cc)) * 512 + d] = sc;
        }
      }
  } else {
    float* O = (float*)out0;
    float sc = p0[0];
#pragma unroll
    for (int mt = 0; mt < 4; mt++)
#pragma unroll
      for (int r = 0; r < 4; r++) {
        int cc = m0 + mh + mt * 16 + q * 4 + r;
#pragma unroll
        for (int nt = 0; nt < 4; nt++) {
          int n = n0 + nh + nt * 16 + lm;
          O[((size_t)(zb * 512 + cc)) * 1024 + n] = sc * acc[mt][nt][r];
        }
      }
  }
}

// conv2 3x3 SAME 256->512, split-bf16 32x32x16 MFMA, register-prefetch pipeline.
// 256 threads, 2 blocks/CU, grid (8 y, 4 co, 16 g) = 512 blocks.
// Block tile 128co x 128px (4 rows). Wave tile 64co x 64px = 2x2 of 32x32.
// K-order: 8 ci-chunks of 32 x 3 dy (3-tap weight groups). 24 phases.
// LDS rows = 128 B (32ci hi | 32ci lo = 8 chunks of 16B), chunk c at slot c^(e&7)
// (8-period swizzle over 8 consecutive lanes -> 2 lanes/bank = free).
// Pipeline: prefetch next phase's weights (+input at chunk boundary) into VGPRs
// BEFORE compute; commit regs->LDS after the compute barrier.
__global__ __launch_bounds__(256, 2) void conv3x3_pipe(
    const unsigned short* __restrict__ Y1thi, const unsigned short* __restrict__ Y1tlo,
    const unsigned short* __restrict__ w2bhi, const unsigned short* __restrict__ w2blo,
    const float* __restrict__ b2, unsigned short* __restrict__ Fhi,
    unsigned short* __restrict__ Flo, float* __restrict__ stats,
    float* __restrict__ rowsum) {
  __shared__ __attribute__((aligned(16))) unsigned char smem[75264];
  const int WOFF = 26112;      // input 204*128 B, weights 384*128 B
  const int WSTRIDE = 393216;  // 3*512*256 elements per dy tap-group
  int t = threadIdx.x;
  int g = blockIdx.z, co_base = blockIdx.y * 128, y0 = blockIdx.x * 4;
  int w = t >> 6, lane = t & 63;
  int l31 = lane & 31, q2 = lane >> 5;
  int co_half = (w & 1) * 64;
  int rb = (w >> 1) * 2;  // wave's first image row within block tile

  // ---- staging descriptors (hoisted; c = chunk slot is j-invariant) ----
  int c = t & 7;
  int e0 = t >> 3;  // 0..31
  const unsigned short* wbase =
      ((c < 4) ? w2bhi : w2blo) + ((size_t)(co_base + e0) * 256 + (c & 3) * 8);
  int wlds0 = WOFF + e0 * 128 + ((c ^ (e0 & 7)) << 4);
  const unsigned short* isel = ((c < 4) ? Y1thi : Y1tlo) + (c & 3) * 8;
  int ioff[7], ilds[7];
  bool ivalid[7], iexists[7];
#pragma unroll
  for (int j = 0; j < 7; j++) {
    int e = e0 + 32 * j;
    int srow = e / 34, sx = e - srow * 34;
    int gy = y0 - 1 + srow, gx = sx - 1;
    iexists[j] = e < 204;
    ivalid[j] = iexists[j] && ((unsigned)gy < 32u) && ((unsigned)gx < 32u);
    ioff[j] = ivalid[j] ? ((g * 32 + gy) * 32 + gx) * 256 : 0;
    ilds[j] = e * 128 + ((c ^ (e & 7)) << 4);
  }
  int selA0 = (q2 ^ (l31 & 7)) << 4;        // A-frag swizzle, k-step 0
  int selA1 = ((2 + q2) ^ (l31 & 7)) << 4;  // k-step 1

  // ---- initial stage: chunk 0, dy 0 ----
#pragma unroll
  for (int j = 0; j < 12; j++)
    *(uint4*)(smem + wlds0 + j * 4096) =
        *(const uint4*)(wbase + (j >> 2) * 131072 + (j & 3) * 8192);
#pragma unroll
  for (int j = 0; j < 7; j++) {
    if (iexists[j]) {
      uint4 v = make_uint4(0u, 0u, 0u, 0u);
      if (ivalid[j]) v = *(const uint4*)(isel + ioff[j]);
      *(uint4*)(smem + ilds[j]) = v;
    }
  }
  __syncthreads();

  facc16 acc[2][2] = {};
  uint4 wreg[12], inreg[7];
  for (int chunk = 0; chunk < 8; chunk++) {
    int ci0 = chunk * 32;
#pragma unroll
    for (int dy = 0; dy < 3; dy++) {
      bool last = (dy == 2) && (chunk == 7);
      // prefetch next phase into registers (latency hides behind MFMA below)
      if (!last) {
        int ndy = (dy == 2) ? 0 : dy + 1;
        int nci = (dy == 2) ? ci0 + 32 : ci0;
        const unsigned short* wp = wbase + ndy * WSTRIDE + nci;
#pragma unroll
        for (int j = 0; j < 12; j++)
          wreg[j] = *(const uint4*)(wp + (j >> 2) * 131072 + (j & 3) * 8192);
        if (dy == 2) {
#pragma unroll
          for (int j = 0; j < 7; j++) {
            inreg[j] = make_uint4(0u, 0u, 0u, 0u);
            if (ivalid[j]) inreg[j] = *(const uint4*)(isel + ioff[j] + nci);
          }
        }
      }
      // compute current phase: 3 dx x 2 k-steps x (2x2 tiles x 3 passes)
#pragma unroll
      for (int dx = 0; dx < 3; dx++) {
#pragma unroll
        for (int s = 0; s < 2; s++) {
          int selA = s ? selA1 : selA0;
          int kc = s * 2 + q2;
          bfrag ah[2], al[2], bh[2], bl[2];
#pragma unroll
          for (int ct = 0; ct < 2; ct++) {
            int off = WOFF + (dx * 128 + co_half + ct * 32 + l31) * 128 + selA;
            ah[ct] = *(const bfrag*)(smem + off);
            al[ct] = *(const bfrag*)(smem + (off ^ 64));
          }
#pragma unroll
          for (int it = 0; it < 2; it++) {
            int ei = (rb + it + dy) * 34 + l31 + dx;
            int off = ei * 128 + ((kc ^ (ei & 7)) << 4);
            bh[it] = *(const bfrag*)(smem + off);
            bl[it] = *(const bfrag*)(smem + (off ^ 64));
          }
#pragma unroll
          for (int ct = 0; ct < 2; ct++)
#pragma unroll
            for (int it = 0; it < 2; it++) {
              acc[ct][it] = __builtin_amdgcn_mfma_f32_32x32x16_bf16(ah[ct], bh[it], acc[ct][it], 0, 0, 0);
              acc[ct][it] = __builtin_amdgcn_mfma_f32_32x32x16_bf16(ah[ct], bl[it], acc[ct][it], 0, 0, 0);
              acc[ct][it] = __builtin_amdgcn_mfma_f32_32x32x16_bf16(al[ct], bh[it], acc[ct][it], 0, 0, 0);
            }
        }
      }
      __syncthreads();
      if (!last) {
#pragma unroll
        for (int j = 0; j < 12; j++) *(uint4*)(smem + wlds0 + j * 4096) = wreg[j];
        if (dy == 2) {
#pragma unroll
          for (int j = 0; j < 7; j++)
            if (iexists[j]) *(uint4*)(smem + ilds[j]) = inreg[j];
        }
        __syncthreads();
      }
    }
  }
  // epilogue: +bias, LeakyReLU, bf16 split store, per-channel stats
  int grp = g >> 3;
#pragma unroll
  for (int ct = 0; ct < 2; ct++)
#pragma unroll
    for (int r = 0; r < 16; r++) {
      int co = co_base + co_half + ct * 32 + (r & 3) + 8 * (r >> 2) + 4 * q2;
      float bb = b2[co];
      float s = 0.f, s2 = 0.f;
#pragma unroll
      for (int it = 0; it < 2; it++) {
        float v = acc[ct][it][r] + bb;
        v = v > 0.f ? v : 0.01f * v;
        unsigned short h = bf16_rn(v);
        unsigned short lo_ = bf16_rn(v - __uint_as_float((unsigned)h << 16));
        size_t o = (size_t)(g * 512 + co) * 1024 + (y0 + rb + it) * 32 + l31;
        Fhi[o] = h;
        Flo[o] = lo_;
        s += v;
        s2 = fmaf(v, v, s2);
      }
#pragma unroll
      for (int d = 1; d <= 16; d <<= 1) {
        s += __shfl_xor(s, d);
        s2 += __shfl_xor(s2, d);
      }
      if (l31 == 0) {
        atomicAdd(&stats[grp * 512 + co], s);
        atomicAdd(&stats[1024 + grp * 512 + co], s2);
        atomicAdd(&rowsum[g * 512 + co], s);
      }
    }
}

// Row softmax over 512; reads S0+S1 (K-split partials), writes att hi/lo in place
// into S0's row (hi ushorts [0:512), lo [512:1024)).
__global__ __launch_bounds__(256) void softmax_rows(float* __restrict__ S) {
  int row = blockIdx.x;
  float* p = S + (size_t)row * 512;
  const float* p1 = p + 2097152;
  int t = threadIdx.x;
  float2 va = *(const float2*)(p + 2 * t);
  float2 vb = *(const float2*)(p1 + 2 * t);
  float vx = va.x + vb.x, vy = va.y + vb.y;
  float mx = fmaxf(vx, vy);
#pragma unroll
  for (int d = 32; d >= 1; d >>= 1) mx = fmaxf(mx, __shfl_xor(mx, d));
  __shared__ float sred[8];
  int wave = t >> 6, lane = t & 63;
  if (lane == 0) sred[wave] = mx;
  __syncthreads();
  float m4 = fmaxf(fmaxf(sred[0], sred[1]), fmaxf(sred[2], sred[3]));
  float ex = expf(vx - m4), ey = expf(vy - m4);
  float s = ex + ey;
#pragma unroll
  for (int d = 32; d >= 1; d >>= 1) s += __shfl_xor(s, d);
  if (lane == 0) sred[4 + wave] = s;
  __syncthreads();
  float inv = 1.f / (sred[4] + sred[5] + sred[6] + sred[7]);
  float px_ = ex * inv, py_ = ey * inv;
  unsigned short h0 = bf16_rn(px_), h1 = bf16_rn(py_);
  unsigned short l0 = bf16_rn(px_ - __uint_as_float((unsigned)h0 << 16));
  unsigned short l1 = bf16_rn(py_ - __uint_as_float((unsigned)h1 << 16));
  unsigned short* rh = (unsigned short*)p;
  *(ushort2*)(rh + 2 * t) = make_ushort2(h0, h1);
  *(ushort2*)(rh + 512 + 2 * t) = make_ushort2(l0, l1);
}

extern "C" void kernel_launch(void* const* d_in, const int* in_sizes, int n_in,
                              void* d_out, int out_size, void* d_ws, size_t ws_size,
                              hipStream_t stream) {
  const float* x = (const float*)d_in[0];
  const float* x1 = (const float*)d_in[1];
  const float* x2 = (const float*)d_in[2];
  const float* w1 = (const float*)d_in[3];
  const float* b1 = (const float*)d_in[4];
  const float* w2 = (const float*)d_in[5];
  const float* b2 = (const float*)d_in[6];
  const float* gamma = (const float*)d_in[7];
  const float* bnb = (const float*)d_in[8];
  const float* beta = (const float*)d_in[9];
  float* out = (float*)d_out;
  float* ws = (float*)d_ws;

  // Region RF [0 : 8388608): x12t -> F(yhat) -> xt
  unsigned short* x12thi = (unsigned short*)ws;             // 16x1024x512
  unsigned short* x12tlo = (unsigned short*)(ws + 4194304);
  unsigned short* Fhi = (unsigned short*)ws;                // 16x512x1024
  unsigned short* Flo = (unsigned short*)(ws + 4194304);
  unsigned short* xthi = (unsigned short*)ws;               // 8x1024x512
  unsigned short* xtlo = (unsigned short*)(ws + 2097152);
  // Region RY [8388608 : 12582912): Y1t -> S0/S1 (att in S0)
  unsigned short* Y1thi = (unsigned short*)(ws + 8388608);  // 16x1024x256
  unsigned short* Y1tlo = (unsigned short*)(ws + 10485760);
  float* S = ws + 8388608;                                  // S0; S1 at +2097152
  // Persistent
  unsigned short* w2bhi = (unsigned short*)(ws + 12582912);
  unsigned short* w2blo = (unsigned short*)(ws + 13172736);
  float* stats = ws + 13762560;   // 2048 (+ rowsum 8192 contiguous)
  float* rowsum = ws + 13764608;

  // w2 prep + zero stats/rowsum
  prep_w2<<<512, 256, 0, stream>>>(w2, w2bhi, w2blo, stats);
  // x1,x2 -> x12t [g][px][ci] hi/lo
  transpose_split<<<dim3(32, 16, 16), 256, 0, stream>>>(x1, x2, x12thi, x12tlo);
  // conv1: D[co][px] = sum_ci w1*x, +b1, emit Y1t [g][px][co] hi/lo
  gemm_nt<512, 0, 1, 0><<<dim3(8, 2, 16), 256, 0, stream>>>(
      w1, nullptr, 512, 0LL, x12thi, x12tlo, 512, 524288LL,
      Y1thi, Y1tlo, b1, nullptr, nullptr, nullptr);
  // conv2 + bias + LeakyReLU -> yhat split + stats + rowsums (pipelined)
  conv3x3_pipe<<<dim3(8, 4, 16), 256, 0, stream>>>(
      Y1thi, Y1tlo, w2bhi, w2blo, b2, Fhi, Flo, stats, rowsum);
  // scores (K-split x2) with BN folded -> S0, S1
  gemm_nt<512, 1, 0, 1><<<dim3(4, 4, 16), 256, 0, stream>>>(
      Fhi, Flo, 1024, 524288LL, Fhi + (size_t)8 * 524288, Flo + (size_t)8 * 524288,
      1024, 524288LL, S, nullptr, stats, rowsum, gamma, bnb);
  // x -> xt [b][px][c] hi/lo (F dead; overwrites RF front)
  transpose_split<<<dim3(32, 16, 8), 256, 0, stream>>>(x, x, xthi, xtlo);
  // softmax (S0+S1) in place -> att hi/lo packed in S0 rows
  softmax_rows<<<4096, 256, 0, stream>>>(S);
  // out: O[c][px] = beta * sum_d att*xt
  gemm_nt<512, 2, 0, 0><<<dim3(8, 4, 8), 256, 0, stream>>>(
      (unsigned short*)S, (unsigned short*)S + 512, 1024, 524288LL,
      xthi, xtlo, 512, 524288LL, out, nullptr, beta, nullptr, nullptr, nullptr);
}

// Round 6
// 318.678 us; speedup vs baseline: 1.5065x; 1.5065x over previous
//
#include <hip/hip_runtime.h>

// Dims: x,x1,x2:(8,512,32,32) fp32; w1:(256,512,1,1); b1:(256); w2:(512,256,3,3);
// b2:(512); gamma,bn_bias:(512); beta:(1). Out:(8,512,32,32) fp32.
// G = 16 images (8 from x1 -> group0, 8 from x2 -> group1), N = 1024 spatial.
//
// ws layout (float offsets), total 13,772,800 fl = 55.09 MB:
//  [0        : 8388608 ) RF : x12t hi/lo -> F=yhat hi/lo (conv2 out) -> xt hi/lo
//  [8388608  : 12582912) RY : Y1t hi/lo (conv1 out) -> S0 + S1 partial; att in S0
//  [12582912 : 13762560) w2s : pre-swizzled weight LDS image, 2,359,296 ushorts
//                        (4 panels x 8 ci-chunks x 3 dy) x 48 KB blocks
//  [13762560 : 13764608) stats (sum, sumsq per group x 512)
//  [13764608 : 13772800) rowsum [16][512]

typedef __attribute__((ext_vector_type(8))) short bfrag;   // 8 bf16 = 4 VGPR
typedef __attribute__((ext_vector_type(4))) float facc;    // 4 fp32 acc

__device__ __forceinline__ unsigned short bf16_rn(float v) {
  unsigned u = __float_as_uint(v);
  return (unsigned short)((u + 0x7fffu + ((u >> 16) & 1u)) >> 16);
}

// async global -> LDS, 16 B per lane. lds must be wave-uniform; HW adds lane*16.
__device__ __forceinline__ void dma16(const void* g, const void* lds) {
  __builtin_amdgcn_global_load_lds(
      (const __attribute__((address_space(1))) unsigned int*)g,
      (__attribute__((address_space(3))) unsigned int*)(unsigned int)(unsigned long long)(const char*)lds,
      16, 0, 0);
}

// Prologue: blocks [0,8192) transpose-split x1/x2 -> x12t [z][px][ci] bf16 hi/lo;
// blocks [8192,8704) build w2s (pre-swizzled weight image) + zero stats.
__global__ __launch_bounds__(256) void prologue(
    const float* __restrict__ x1, const float* __restrict__ x2,
    const float* __restrict__ w2,
    unsigned short* __restrict__ hi, unsigned short* __restrict__ lo,
    unsigned short* __restrict__ w2s, float* __restrict__ statsz) {
  int bid = blockIdx.x;
  int t = threadIdx.x;
  if (bid < 8192) {
    __shared__ float tile[32][33];
    int p0 = (bid & 31) * 32, ci0 = ((bid >> 5) & 15) * 32, z = bid >> 9;
    const float* src = (z < 8) ? x1 + (size_t)z * 524288 : x2 + (size_t)(z - 8) * 524288;
    {
      int ci_l = t >> 5, p_l = t & 31;
#pragma unroll
      for (int j = 0; j < 4; j++)
        tile[ci_l + 8 * j][p_l] = src[(size_t)(ci0 + ci_l + 8 * j) * 1024 + p0 + p_l];
    }
    __syncthreads();
    {
      int p_l = t >> 3, cg = (t & 7) * 4;
      unsigned short hh[4], ll[4];
#pragma unroll
      for (int j = 0; j < 4; j++) {
        float v = tile[cg + j][p_l];
        hh[j] = bf16_rn(v);
        ll[j] = bf16_rn(v - __uint_as_float((unsigned)hh[j] << 16));
      }
      size_t idx = ((size_t)z * 1024 + p0 + p_l) * 512 + ci0 + cg;
      *(ushort4*)(hi + idx) = make_ushort4(hh[0], hh[1], hh[2], hh[3]);
      *(ushort4*)(lo + idx) = make_ushort4(ll[0], ll[1], ll[2], ll[3]);
    }
  } else {
    int co = bid - 8192;  // 0..511
    if (co < 40) statsz[co * 256 + t] = 0.f;
    int panel = co >> 7, co_l = co & 127;
    int ch = t >> 5, ci_l = t & 31;
    int chi = ci_l >> 3, cil7 = ci_l & 7;
    const float* src = w2 + ((size_t)co * 256 + t) * 9;
#pragma unroll
    for (int tap = 0; tap < 9; tap++) {
      float v = src[tap];
      unsigned short h = bf16_rn(v);
      unsigned short l = bf16_rn(v - __uint_as_float((unsigned)h << 16));
      int dy = tap / 3, slot = tap % 3;
      int e = slot * 128 + co_l;
      size_t base = (size_t)(((panel * 8 + ch) * 3 + dy)) * 24576;
      size_t off_hi = base + e * 64 + ((chi ^ (e & 7)) << 3) + cil7;
      w2s[off_hi] = h;
      w2s[off_hi ^ 32] = l;  // chunk c+4 slot differs by XOR 4 -> 32 ushorts
    }
  }
}

// fp32 [z][512 ci][1024 px] -> [z][px][512 ci] bf16 hi/lo. z<8: src0, z>=8: src1.
__global__ __launch_bounds__(256) void transpose_split(
    const float* __restrict__ src0, const float* __restrict__ src1,
    unsigned short* __restrict__ hi, unsigned short* __restrict__ lo) {
  __shared__ float tile[32][33];
  int z = blockIdx.z;
  const float* src = (z < 8) ? src0 + (size_t)z * 524288 : src1 + (size_t)(z - 8) * 524288;
  int ci0 = blockIdx.y * 32, p0 = blockIdx.x * 32;
  int t = threadIdx.x;
  {
    int ci_l = t >> 5, p_l = t & 31;
#pragma unroll
    for (int j = 0; j < 4; j++)
      tile[ci_l + 8 * j][p_l] = src[(size_t)(ci0 + ci_l + 8 * j) * 1024 + p0 + p_l];
  }
  __syncthreads();
  {
    int p_l = t >> 3, cg = (t & 7) * 4;
    unsigned short hh[4], ll[4];
#pragma unroll
    for (int j = 0; j < 4; j++) {
      float v = tile[cg + j][p_l];
      hh[j] = bf16_rn(v);
      ll[j] = bf16_rn(v - __uint_as_float((unsigned)hh[j] << 16));
    }
    size_t idx = ((size_t)z * 1024 + p0 + p_l) * 512 + ci0 + cg;
    *(ushort4*)(hi + idx) = make_ushort4(hh[0], hh[1], hh[2], hh[3]);
    *(ushort4*)(lo + idx) = make_ushort4(ll[0], ll[1], ll[2], ll[3]);
  }
}

// Split-bf16 3-pass NT MFMA GEMM: D[m][n] = sum_k A[m][k]*B[n][k].
// Block 128x128, 4 waves 2x2, wave = 4x4 tiles of 16x16x32, K-step 64.
// AF32=1: A is fp32 (w1), split in-register during staging.
// KSPLIT=1: blockIdx.z = kh*8 + zb; EPI1 writes partial S to S + kh*2097152,
//           affine terms only when kh==0.
// EPI 0: +bias[m], emit bf16 hi/lo transposed [z][n][m] (conv1 -> Y1t)
// EPI 1: BN-folded scores epilogue -> S fp32 [z][m][n]
// EPI 2: fp32 store out[z][m][n] * p0[0]
template <int KTOT, int EPI, int AF32, int KSPLIT>
__global__ __launch_bounds__(256, 2) void gemm_nt(
    const void* __restrict__ Ahi_, const unsigned short* __restrict__ Alo,
    int aLD, long long aBS,
    const unsigned short* __restrict__ Bhi, const unsigned short* __restrict__ Blo,
    int bLD, long long bBS,
    void* __restrict__ out0, void* __restrict__ out1,
    const float* __restrict__ p0, const float* __restrict__ p1,
    const float* __restrict__ p2, const float* __restrict__ p3) {
  __shared__ __attribute__((aligned(16))) unsigned char smem[65536];
  int t = threadIdx.x;
  int z = blockIdx.z;
  int zb = z, kh = 0;
  if (KSPLIT) { zb = z & 7; kh = z >> 3; }
  int m0 = blockIdx.y * 128, n0 = blockIdx.x * 128;
  int w = t >> 6, lane = t & 63;
  int lm = lane & 15, q = lane >> 4;
  int mh = (w & 1) * 64, nh = (w >> 1) * 64;
  facc acc[4][4] = {};  // [mt][nt]
  for (int k0 = 0; k0 < KTOT; k0 += 64) {
    __syncthreads();
    if (AF32) {
      const float* Af = (const float*)Ahi_ + (size_t)zb * aBS;
#pragma unroll
      for (int j = 0; j < 8; j++) {
        int idx = t + 256 * j;
        int row = idx >> 4, c4 = idx & 15;
        float4 v = *(const float4*)(Af + (size_t)(m0 + row) * aLD + k0 + c4 * 4);
        unsigned short h0 = bf16_rn(v.x), h1 = bf16_rn(v.y), h2 = bf16_rn(v.z), h3 = bf16_rn(v.w);
        unsigned short l0 = bf16_rn(v.x - __uint_as_float((unsigned)h0 << 16));
        unsigned short l1 = bf16_rn(v.y - __uint_as_float((unsigned)h1 << 16));
        unsigned short l2 = bf16_rn(v.z - __uint_as_float((unsigned)h2 << 16));
        unsigned short l3 = bf16_rn(v.w - __uint_as_float((unsigned)h3 << 16));
        int base = row * 256 + (((c4 >> 1) ^ (row & 7)) * 16) + (c4 & 1) * 8;
        *(ushort4*)(smem + base) = make_ushort4(h0, h1, h2, h3);
        *(ushort4*)(smem + base + 128) = make_ushort4(l0, l1, l2, l3);
      }
    } else {
      const unsigned short* Ah = (const unsigned short*)Ahi_ + (size_t)zb * aBS + kh * KTOT;
      const unsigned short* Al = Alo + (size_t)zb * aBS + kh * KTOT;
#pragma unroll
      for (int j = 0; j < 8; j++) {
        int idx = t + 256 * j;
        int row = idx >> 4, c = idx & 15;
        const unsigned short* src = (c < 8) ? Ah : Al;
        uint4 v = *(const uint4*)(src + (size_t)(m0 + row) * aLD + k0 + (c & 7) * 8);
        *(uint4*)(smem + row * 256 + ((((c & 7) ^ (row & 7)) | (c & 8)) * 16)) = v;
      }
    }
#pragma unroll
    for (int j = 0; j < 8; j++) {
      int idx = t + 256 * j;
      int row = idx >> 4, c = idx & 15;
      const unsigned short* src = (c < 8) ? Bhi : Blo;
      uint4 v = *(const uint4*)(src + (size_t)zb * bBS + (size_t)kh * KTOT +
                                (size_t)(n0 + row) * bLD + k0 + (c & 7) * 8);
      *(uint4*)(smem + 32768 + row * 256 + ((((c & 7) ^ (row & 7)) | (c & 8)) * 16)) = v;
    }
    __syncthreads();
#pragma unroll
    for (int ks = 0; ks < 2; ks++) {
      bfrag ah[4], al[4], bh[4], bl[4];
#pragma unroll
      for (int mt = 0; mt < 4; mt++) {
        int m = mh + mt * 16 + lm;
        int phys = ((ks * 4 + q) ^ (m & 7)) * 16;
        const unsigned char* p = smem + m * 256;
        ah[mt] = *(const bfrag*)(p + phys);
        al[mt] = *(const bfrag*)(p + phys + 128);
      }
#pragma unroll
      for (int nt = 0; nt < 4; nt++) {
        int n = nh + nt * 16 + lm;
        int phys = ((ks * 4 + q) ^ (n & 7)) * 16;
        const unsigned char* p = smem + 32768 + n * 256;
        bh[nt] = *(const bfrag*)(p + phys);
        bl[nt] = *(const bfrag*)(p + phys + 128);
      }
#pragma unroll
      for (int mt = 0; mt < 4; mt++)
#pragma unroll
        for (int nt = 0; nt < 4; nt++) {
          acc[mt][nt] = __builtin_amdgcn_mfma_f32_16x16x32_bf16(ah[mt], bh[nt], acc[mt][nt], 0, 0, 0);
          acc[mt][nt] = __builtin_amdgcn_mfma_f32_16x16x32_bf16(ah[mt], bl[nt], acc[mt][nt], 0, 0, 0);
          acc[mt][nt] = __builtin_amdgcn_mfma_f32_16x16x32_bf16(al[mt], bh[nt], acc[mt][nt], 0, 0, 0);
        }
    }
  }
  if (EPI == 0) {
    unsigned short* Oh = (unsigned short*)out0;
    unsigned short* Ol = (unsigned short*)out1;
#pragma unroll
    for (int mt = 0; mt < 4; mt++) {
      int mb = m0 + mh + mt * 16 + q * 4;
#pragma unroll
      for (int nt = 0; nt < 4; nt++) {
        int n = n0 + nh + nt * 16 + lm;
        unsigned short hh[4], ll[4];
#pragma unroll
        for (int r = 0; r < 4; r++) {
          float v = acc[mt][nt][r] + p0[mb + r];
          hh[r] = bf16_rn(v);
          ll[r] = bf16_rn(v - __uint_as_float((unsigned)hh[r] << 16));
        }
        size_t o = ((size_t)(zb * 1024 + n)) * 256 + mb;
        *(ushort4*)(Oh + o) = make_ushort4(hh[0], hh[1], hh[2], hh[3]);
        *(ushort4*)(Ol + o) = make_ushort4(ll[0], ll[1], ll[2], ll[3]);
      }
    }
  } else if (EPI == 1) {
    // S = a1*a2*G (+ kh==0: a1*t2*r1 + t1*a2*r2 + 1024*t1*t2)
    float* S = (float*)out0 + (size_t)kh * 2097152;
    const float* stats = p0;
    const float* rowsum = p1;
    const float* gamma = p2;
    const float* bnb = p3;
    float a2v[4], t2v[4], r2v[4];
#pragma unroll
    for (int nt = 0; nt < 4; nt++) {
      int d = n0 + nh + nt * 16 + lm;
      float mu = stats[512 + d] * (1.f / 8192.f);
      float var = stats[1536 + d] * (1.f / 8192.f) - mu * mu;
      float a = gamma[d] * rsqrtf(var + 1e-5f);
      a2v[nt] = a;
      t2v[nt] = bnb[d] - mu * a;
      r2v[nt] = rowsum[(8 + zb) * 512 + d];
    }
#pragma unroll
    for (int mt = 0; mt < 4; mt++)
#pragma unroll
      for (int r = 0; r < 4; r++) {
        int cc = m0 + mh + mt * 16 + q * 4 + r;
        float mu = stats[cc] * (1.f / 8192.f);
        float var = stats[1024 + cc] * (1.f / 8192.f) - mu * mu;
        float a1 = gamma[cc] * rsqrtf(var + 1e-5f);
        float t1 = bnb[cc] - mu * a1;
        float r1 = rowsum[zb * 512 + cc];
#pragma unroll
        for (int nt = 0; nt < 4; nt++) {
          int d = n0 + nh + nt * 16 + lm;
          float sc = a1 * a2v[nt] * acc[mt][nt][r];
          if (kh == 0)
            sc += a1 * t2v[nt] * r1 + t1 * a2v[nt] * r2v[nt] + 1024.f * t1 * t2v[nt];
          S[((size_t)(zb * 512 + cc)) * 512 + d] = sc;
        }
      }
  } else {
    float* O = (float*)out0;
    float sc = p0[0];
#pragma unroll
    for (int mt = 0; mt < 4; mt++)
#pragma unroll
      for (int r = 0; r < 4; r++) {
        int cc = m0 + mh + mt * 16 + q * 4 + r;
#pragma unroll
        for (int nt = 0; nt < 4; nt++) {
          int n = n0 + nh + nt * 16 + lm;
          O[((size_t)(zb * 512 + cc)) * 1024 + n] = sc * acc[mt][nt][r];
        }
      }
  }
}

// conv2 3x3 SAME 256->512 split-bf16 MFMA implicit GEMM (round-3 core).
// Block: 128 co x 128 px (4 image rows), 4 waves 2x2, 16x16x32 MFMA, 0 conflicts.
// Weights staged via global_load_lds from pre-swizzled w2s (12 DMA/wave/phase);
// input staged via VGPR path once per ci-chunk (dy==0).
__global__ __launch_bounds__(256, 2) void conv3x3_mfma(
    const unsigned short* __restrict__ Y1thi, const unsigned short* __restrict__ Y1tlo,
    const unsigned short* __restrict__ w2s,
    const float* __restrict__ b2, unsigned short* __restrict__ Fhi,
    unsigned short* __restrict__ Flo, float* __restrict__ stats,
    float* __restrict__ rowsum) {
  __shared__ __attribute__((aligned(16))) unsigned char smem[75264];
  const int WOFF = 26112;  // input 204*128 B, then 384*128 B weights
  int t = threadIdx.x;
  int g = blockIdx.z;
  int panel = blockIdx.y;
  int co_base = panel * 128;
  int y0 = blockIdx.x * 4;
  int w = t >> 6, lane = t & 63;
  int lm = lane & 15, q = lane >> 4;
  int co_half = (w & 1) * 64, px_half = (w >> 1) * 64;
  int px_l[4], row_l[4], x_l[4];
#pragma unroll
  for (int i = 0; i < 4; i++) {
    px_l[i] = px_half + i * 16 + lm;
    row_l[i] = px_l[i] >> 5;
    x_l[i] = px_l[i] & 31;
  }
  const unsigned char* wgbase =
      (const unsigned char*)w2s + (size_t)panel * 8 * 3 * 49152 + w * 12288 + lane * 16;
  const unsigned char* ldsw = smem + WOFF + w * 12288;
  facc acc[4][4] = {};  // [cotile][pxtile]
  for (int chunk = 0; chunk < 8; chunk++) {
    int ci0 = chunk * 32;
    for (int dy = 0; dy < 3; dy++) {
      __syncthreads();
      // weights: 12 x 1KB async DMA per wave (pre-swizzled image)
      {
        const unsigned char* gsrc = wgbase + (size_t)(chunk * 3 + dy) * 49152;
#pragma unroll
        for (int j = 0; j < 12; j++) dma16(gsrc + j * 1024, ldsw + j * 1024);
      }
      if (dy == 0) {
        // stage input chunk: 204 entries x 8 chunks of 16B (hi c=0..3, lo c=4..7)
        for (int u = t; u < 1632; u += 256) {
          int e = u >> 3, c = u & 7;
          int srow = e / 34, xh = e - srow * 34;
          int gy = y0 - 1 + srow, gx = xh - 1;
          uint4 v = make_uint4(0u, 0u, 0u, 0u);
          if ((unsigned)gy < 32u && (unsigned)gx < 32u) {
            const unsigned short* src = (c < 4) ? Y1thi : Y1tlo;
            v = *(const uint4*)(src +
                ((size_t)((g * 32 + gy) * 32 + gx) * 256 + ci0 + (c & 3) * 8));
          }
          *(uint4*)(smem + e * 128 + ((c ^ (xh & 7)) * 16)) = v;
        }
      }
      __syncthreads();
#pragma unroll
      for (int dx = 0; dx < 3; dx++) {
        bfrag ah[4], al[4], bh[4], bl[4];
#pragma unroll
        for (int j = 0; j < 4; j++) {
          int cr = co_half + j * 16 + lm;
          const unsigned char* p = smem + WOFF + dx * 16384 + cr * 128;
          int ph = (q ^ (lm & 7)) * 16;
          ah[j] = *(const bfrag*)(p + ph);
          al[j] = *(const bfrag*)(p + (ph ^ 64));
        }
#pragma unroll
        for (int i = 0; i < 4; i++) {
          int xh = x_l[i] + dx;
          int entry = (row_l[i] + dy) * 34 + xh;
          const unsigned char* p = smem + entry * 128;
          int ph = (q ^ (xh & 7)) * 16;
          bh[i] = *(const bfrag*)(p + ph);
          bl[i] = *(const bfrag*)(p + (ph ^ 64));
        }
#pragma unroll
        for (int j = 0; j < 4; j++)
#pragma unroll
          for (int i = 0; i < 4; i++) {
            acc[j][i] = __builtin_amdgcn_mfma_f32_16x16x32_bf16(ah[j], bh[i], acc[j][i], 0, 0, 0);
            acc[j][i] = __builtin_amdgcn_mfma_f32_16x16x32_bf16(ah[j], bl[i], acc[j][i], 0, 0, 0);
            acc[j][i] = __builtin_amdgcn_mfma_f32_16x16x32_bf16(al[j], bh[i], acc[j][i], 0, 0, 0);
          }
      }
    }
  }
  // epilogue: +bias, LeakyReLU, bf16 split store, stats + rowsums
  int grp = g >> 3;
  int px0 = blockIdx.x * 128;
#pragma unroll
  for (int j = 0; j < 4; j++) {
#pragma unroll
    for (int r = 0; r < 4; r++) {
      int co = co_base + co_half + j * 16 + q * 4 + r;
      float bb = b2[co];
      float s = 0.f, s2 = 0.f;
#pragma unroll
      for (int i = 0; i < 4; i++) {
        float v = acc[j][i][r] + bb;
        v = v > 0.f ? v : 0.01f * v;
        unsigned short h = bf16_rn(v);
        unsigned short l = bf16_rn(v - __uint_as_float((unsigned)h << 16));
        size_t o = ((size_t)(g * 512 + co)) * 1024 + px0 + px_l[i];
        Fhi[o] = h;
        Flo[o] = l;
        s += v;
        s2 = fmaf(v, v, s2);
      }
#pragma unroll
      for (int d = 1; d <= 8; d <<= 1) {
        s += __shfl_xor(s, d);
        s2 += __shfl_xor(s2, d);
      }
      if (lm == 0) {
        atomicAdd(&stats[grp * 512 + co], s);
        atomicAdd(&stats[1024 + grp * 512 + co], s2);
        atomicAdd(&rowsum[g * 512 + co], s);
      }
    }
  }
}

// Row softmax over 512; reads S0+S1 (K-split partials), writes att hi/lo in place
// into S0's row (hi ushorts [0:512), lo [512:1024)).
__global__ __launch_bounds__(256) void softmax_rows(float* __restrict__ S) {
  int row = blockIdx.x;
  float* p = S + (size_t)row * 512;
  const float* p1 = p + 2097152;
  int t = threadIdx.x;
  float2 va = *(const float2*)(p + 2 * t);
  float2 vb = *(const float2*)(p1 + 2 * t);
  float vx = va.x + vb.x, vy = va.y + vb.y;
  float mx = fmaxf(vx, vy);
#pragma unroll
  for (int d = 32; d >= 1; d >>= 1) mx = fmaxf(mx, __shfl_xor(mx, d));
  __shared__ float sred[8];
  int wave = t >> 6, lane = t & 63;
  if (lane == 0) sred[wave] = mx;
  __syncthreads();
  float m4 = fmaxf(fmaxf(sred[0], sred[1]), fmaxf(sred[2], sred[3]));
  float ex = expf(vx - m4), ey = expf(vy - m4);
  float s = ex + ey;
#pragma unroll
  for (int d = 32; d >= 1; d >>= 1) s += __shfl_xor(s, d);
  if (lane == 0) sred[4 + wave] = s;
  __syncthreads();
  float inv = 1.f / (sred[4] + sred[5] + sred[6] + sred[7]);
  float px_ = ex * inv, py_ = ey * inv;
  unsigned short h0 = bf16_rn(px_), h1 = bf16_rn(py_);
  unsigned short l0 = bf16_rn(px_ - __uint_as_float((unsigned)h0 << 16));
  unsigned short l1 = bf16_rn(py_ - __uint_as_float((unsigned)h1 << 16));
  unsigned short* rh = (unsigned short*)p;
  *(ushort2*)(rh + 2 * t) = make_ushort2(h0, h1);
  *(ushort2*)(rh + 512 + 2 * t) = make_ushort2(l0, l1);
}

extern "C" void kernel_launch(void* const* d_in, const int* in_sizes, int n_in,
                              void* d_out, int out_size, void* d_ws, size_t ws_size,
                              hipStream_t stream) {
  const float* x = (const float*)d_in[0];
  const float* x1 = (const float*)d_in[1];
  const float* x2 = (const float*)d_in[2];
  const float* w1 = (const float*)d_in[3];
  const float* b1 = (const float*)d_in[4];
  const float* w2 = (const float*)d_in[5];
  const float* b2 = (const float*)d_in[6];
  const float* gamma = (const float*)d_in[7];
  const float* bnb = (const float*)d_in[8];
  const float* beta = (const float*)d_in[9];
  float* out = (float*)d_out;
  float* ws = (float*)d_ws;

  // Region RF [0 : 8388608): x12t -> F(yhat) -> xt
  unsigned short* x12thi = (unsigned short*)ws;             // 16x1024x512
  unsigned short* x12tlo = (unsigned short*)(ws + 4194304);
  unsigned short* Fhi = (unsigned short*)ws;                // 16x512x1024
  unsigned short* Flo = (unsigned short*)(ws + 4194304);
  unsigned short* xthi = (unsigned short*)ws;               // 8x1024x512
  unsigned short* xtlo = (unsigned short*)(ws + 2097152);
  // Region RY [8388608 : 12582912): Y1t -> S0/S1 (att in S0)
  unsigned short* Y1thi = (unsigned short*)(ws + 8388608);  // 16x1024x256
  unsigned short* Y1tlo = (unsigned short*)(ws + 10485760);
  float* S = ws + 8388608;                                  // S0; S1 at +2097152
  // Persistent
  unsigned short* w2s = (unsigned short*)(ws + 12582912);   // 2,359,296 ushorts
  float* stats = ws + 13762560;   // 2048 (+ rowsum 8192 contiguous)
  float* rowsum = ws + 13764608;

  // prologue: x1/x2 transpose-split + w2s build + stats zero
  prologue<<<8704, 256, 0, stream>>>(x1, x2, w2, x12thi, x12tlo, w2s, stats);
  // conv1: D[co][px] = sum_ci w1*x, +b1, emit Y1t [g][px][co] hi/lo
  gemm_nt<512, 0, 1, 0><<<dim3(8, 2, 16), 256, 0, stream>>>(
      w1, nullptr, 512, 0LL, x12thi, x12tlo, 512, 524288LL,
      Y1thi, Y1tlo, b1, nullptr, nullptr, nullptr);
  // conv2 + bias + LeakyReLU -> yhat split + stats + rowsums
  conv3x3_mfma<<<dim3(8, 4, 16), 256, 0, stream>>>(
      Y1thi, Y1tlo, w2s, b2, Fhi, Flo, stats, rowsum);
  // scores (K-split x2) with BN folded -> S0, S1
  gemm_nt<512, 1, 0, 1><<<dim3(4, 4, 16), 256, 0, stream>>>(
      Fhi, Flo, 1024, 524288LL, Fhi + (size_t)8 * 524288, Flo + (size_t)8 * 524288,
      1024, 524288LL, S, nullptr, stats, rowsum, gamma, bnb);
  // x -> xt [b][px][c] hi/lo (F dead; overwrites RF front)
  transpose_split<<<dim3(32, 16, 8), 256, 0, stream>>>(x, x, xthi, xtlo);
  // softmax (S0+S1) in place -> att hi/lo packed in S0 rows
  softmax_rows<<<4096, 256, 0, stream>>>(S);
  // out: O[c][px] = beta * sum_d att*xt
  gemm_nt<512, 2, 0, 0><<<dim3(8, 4, 8), 256, 0, stream>>>(
      (unsigned short*)S, (unsigned short*)S + 512, 1024, 524288LL,
      xthi, xtlo, 512, 524288LL, out, nullptr, beta, nullptr, nullptr, nullptr);
}

// Round 7
// 291.307 us; speedup vs baseline: 1.6481x; 1.0940x over previous
//
#include <hip/hip_runtime.h>

// Dims: x,x1,x2:(8,512,32,32) fp32; w1:(256,512,1,1); b1:(256); w2:(512,256,3,3);
// b2:(512); gamma,bn_bias:(512); beta:(1). Out:(8,512,32,32) fp32.
// G = 16 images (8 from x1, 8 from x2), N = 1024 spatial.
//
// All GEMM operands are stored as pre-swizzled "LDS images": per (z, panel(128
// rows), kc(64 k)) a 32 KB block of 128 rows x 256 B; row r holds 16 chunks of
// 16 B at slot ((c&7)^(r&7))|(c&8); hi chunks c=0..7 (k=c*8+e), lo c=8..15
// (always hi+128 B). Staging is then pure global_load_lds.
//
// ws layout (byte offsets), total 55,091,200 B (same as round 6):
//  [0        , 33554432) RF : x12t image -> F image (conv2 out) -> xt image
//                         [0,16777216) + att image [16777216, 25165824)
//  [33554432 , 50331648) RY : Y1 conv-input image (16,777,216 B exactly)
//                         -> S0 fp32 [33554432,+8388608) + S1 [+8388608)
//  [50331648 , 55050240) w2s pre-swizzled weight image (round-6 format)
//  [55050240 , 55058432) stats ; [55058432, 55091200) rowsum

typedef __attribute__((ext_vector_type(8))) short bfrag;   // 8 bf16 = 4 VGPR
typedef __attribute__((ext_vector_type(4))) float facc;    // 4 fp32 acc

__device__ __forceinline__ unsigned short bf16_rn(float v) {
  unsigned u = __float_as_uint(v);
  return (unsigned short)((u + 0x7fffu + ((u >> 16) & 1u)) >> 16);
}

// async global -> LDS, 16 B per lane; global addr is per-lane (include lane*16),
// LDS base is wave-uniform (HW adds lane*16).
__device__ __forceinline__ void dma16(const void* g, const void* lds) {
  __builtin_amdgcn_global_load_lds(
      (const __attribute__((address_space(1))) unsigned int*)g,
      (__attribute__((address_space(3))) unsigned int*)(unsigned int)(unsigned long long)(const char*)lds,
      16, 0, 0);
}

// Prologue: blocks [0,8192): x1/x2 -> x12t image; blocks [8192,8704): w2s + stats zero.
__global__ __launch_bounds__(256) void prologue(
    const float* __restrict__ x1, const float* __restrict__ x2,
    const float* __restrict__ w2, unsigned char* __restrict__ x12timg,
    unsigned short* __restrict__ w2s, float* __restrict__ statsz) {
  int bid = blockIdx.x;
  int t = threadIdx.x;
  if (bid < 8192) {
    __shared__ float tile[32][33];
    int p0 = (bid & 31) * 32, ci0 = ((bid >> 5) & 15) * 32, z = bid >> 9;
    const float* src = (z < 8) ? x1 + (size_t)z * 524288 : x2 + (size_t)(z - 8) * 524288;
    {
      int ci_l = t >> 5, p_l = t & 31;
#pragma unroll
      for (int j = 0; j < 4; j++)
        tile[ci_l + 8 * j][p_l] = src[(size_t)(ci0 + ci_l + 8 * j) * 1024 + p0 + p_l];
    }
    __syncthreads();
    {
      int p_l = t >> 3, cg = (t & 7) * 4;
      unsigned short hh[4], ll[4];
#pragma unroll
      for (int j = 0; j < 4; j++) {
        float v = tile[cg + j][p_l];
        hh[j] = bf16_rn(v);
        ll[j] = bf16_rn(v - __uint_as_float((unsigned)hh[j] << 16));
      }
      int px = p0 + p_l, row = px & 127, panel = px >> 7;
      int c = ci0 + cg, kc = c >> 6, ck = (c >> 3) & 7;
      int slot = ck ^ (row & 7);
      size_t byte = (((size_t)(z * 8 + panel) * 8 + kc) * 128 + row) * 256 + slot * 16 + (c & 7) * 2;
      *(ushort4*)(x12timg + byte) = make_ushort4(hh[0], hh[1], hh[2], hh[3]);
      *(ushort4*)(x12timg + byte + 128) = make_ushort4(ll[0], ll[1], ll[2], ll[3]);
    }
  } else {
    int co = bid - 8192;  // 0..511
    if (co < 40) statsz[co * 256 + t] = 0.f;
    int panel = co >> 7, co_l = co & 127;
    int ch = t >> 5, ci_l = t & 31;
    int chi = ci_l >> 3, cil7 = ci_l & 7;
    const float* src = w2 + ((size_t)co * 256 + t) * 9;
#pragma unroll
    for (int tap = 0; tap < 9; tap++) {
      float v = src[tap];
      unsigned short h = bf16_rn(v);
      unsigned short l = bf16_rn(v - __uint_as_float((unsigned)h << 16));
      int dy = tap / 3, slot = tap % 3;
      int e = slot * 128 + co_l;
      size_t base = (size_t)(((panel * 8 + ch) * 3 + dy)) * 24576;
      size_t off_hi = base + e * 64 + ((chi ^ (e & 7)) << 3) + cil7;
      w2s[off_hi] = h;
      w2s[off_hi ^ 32] = l;
    }
  }
}

// x fp32 [z][512 c][1024 px] -> xt image (B operand rows=px, k=c).
__global__ __launch_bounds__(256) void transpose_split_x(
    const float* __restrict__ x, unsigned char* __restrict__ img) {
  __shared__ float tile[32][33];
  int z = blockIdx.z;
  const float* src = x + (size_t)z * 524288;
  int ci0 = blockIdx.y * 32, p0 = blockIdx.x * 32;
  int t = threadIdx.x;
  {
    int ci_l = t >> 5, p_l = t & 31;
#pragma unroll
    for (int j = 0; j < 4; j++)
      tile[ci_l + 8 * j][p_l] = src[(size_t)(ci0 + ci_l + 8 * j) * 1024 + p0 + p_l];
  }
  __syncthreads();
  {
    int p_l = t >> 3, cg = (t & 7) * 4;
    unsigned short hh[4], ll[4];
#pragma unroll
    for (int j = 0; j < 4; j++) {
      float v = tile[cg + j][p_l];
      hh[j] = bf16_rn(v);
      ll[j] = bf16_rn(v - __uint_as_float((unsigned)hh[j] << 16));
    }
    int px = p0 + p_l, row = px & 127, panel = px >> 7;
    int c = ci0 + cg, kc = c >> 6, ck = (c >> 3) & 7;
    int slot = ck ^ (row & 7);
    size_t byte = (((size_t)(z * 8 + panel) * 8 + kc) * 128 + row) * 256 + slot * 16 + (c & 7) * 2;
    *(ushort4*)(img + byte) = make_ushort4(hh[0], hh[1], hh[2], hh[3]);
    *(ushort4*)(img + byte + 128) = make_ushort4(ll[0], ll[1], ll[2], ll[3]);
  }
}

// Split-bf16 3-pass NT MFMA GEMM on pre-swizzled images.
// Block tile 128m x 64n, 256 threads, 4 waves 2x2, wave tile 64m x 32n
// (4x2 tiles of 16x16x32). K-step 64. A/B staged via global_load_lds (image
// memcpy); AF32=1: A is fp32 w1, split in-register. KSPLIT: z = kh*8+zb,
// kc = kh*(KTOT/64)+k0/64, EPI1 partial to S+kh*2097152 (affine only kh==0).
// EPI 0: +bias[m], write conv2-input image. EPI 1: BN-folded scores -> S fp32.
// EPI 2: fp32 out * p0[0].
template <int KTOT, int EPI, int AF32, int KSPLIT>
__global__ __launch_bounds__(256, 2) void gemm_nt(
    const void* __restrict__ Asrc, long long aZS, int aKC,
    const unsigned char* __restrict__ Bimg, long long bZS, int bKC,
    void* __restrict__ out0,
    const float* __restrict__ p0, const float* __restrict__ p1,
    const float* __restrict__ p2, const float* __restrict__ p3) {
  __shared__ __attribute__((aligned(16))) unsigned char smem[49152];
  int t = threadIdx.x;
  int z = blockIdx.z;
  int zb = z, kh = 0;
  if (KSPLIT) { zb = z & 7; kh = z >> 3; }
  int m0 = blockIdx.y * 128, n0 = blockIdx.x * 64;
  int w = t >> 6, lane = t & 63;
  int lm = lane & 15, q = lane >> 4;
  int mh = (w & 1) * 64, nh = (w >> 1) * 32;
  const unsigned char* Abase = (const unsigned char*)Asrc + (size_t)zb * aZS +
      (size_t)(m0 >> 7) * ((size_t)aKC << 15) + (size_t)w * 8192 + (size_t)lane * 16;
  const unsigned char* Bbase = Bimg + (size_t)zb * bZS +
      (size_t)(n0 >> 7) * ((size_t)bKC << 15) + (size_t)(n0 & 127) * 256 +
      (size_t)w * 4096 + (size_t)lane * 16;
  facc acc[4][2] = {};  // [mt][nt]
  for (int k0 = 0; k0 < KTOT; k0 += 64) {
    int kc = (KSPLIT ? kh * (KTOT / 64) : 0) + (k0 >> 6);
    __syncthreads();
    if (AF32) {
      const float* Af = (const float*)Asrc;
#pragma unroll
      for (int j = 0; j < 8; j++) {
        int idx = t + 256 * j;
        int row = idx >> 4, c4 = idx & 15;
        float4 v = *(const float4*)(Af + (size_t)(m0 + row) * KTOT + k0 + c4 * 4);
        unsigned short h0 = bf16_rn(v.x), h1 = bf16_rn(v.y), h2 = bf16_rn(v.z), h3 = bf16_rn(v.w);
        unsigned short l0 = bf16_rn(v.x - __uint_as_float((unsigned)h0 << 16));
        unsigned short l1 = bf16_rn(v.y - __uint_as_float((unsigned)h1 << 16));
        unsigned short l2 = bf16_rn(v.z - __uint_as_float((unsigned)h2 << 16));
        unsigned short l3 = bf16_rn(v.w - __uint_as_float((unsigned)h3 << 16));
        int base = row * 256 + (((c4 >> 1) ^ (row & 7)) * 16) + (c4 & 1) * 8;
        *(ushort4*)(smem + base) = make_ushort4(h0, h1, h2, h3);
        *(ushort4*)(smem + base + 128) = make_ushort4(l0, l1, l2, l3);
      }
    } else {
      const unsigned char* ap = Abase + ((size_t)kc << 15);
#pragma unroll
      for (int j = 0; j < 8; j++) dma16(ap + j * 1024, smem + w * 8192 + j * 1024);
    }
    {
      const unsigned char* bp = Bbase + ((size_t)kc << 15);
#pragma unroll
      for (int j = 0; j < 4; j++) dma16(bp + j * 1024, smem + 32768 + w * 4096 + j * 1024);
    }
    __syncthreads();
#pragma unroll
    for (int ks = 0; ks < 2; ks++) {
      bfrag ah[4], al[4], bh[2], bl[2];
#pragma unroll
      for (int mt = 0; mt < 4; mt++) {
        int m = mh + mt * 16 + lm;
        int phys = ((ks * 4 + q) ^ (m & 7)) * 16;
        const unsigned char* p = smem + m * 256 + phys;
        ah[mt] = *(const bfrag*)p;
        al[mt] = *(const bfrag*)(p + 128);
      }
#pragma unroll
      for (int nt = 0; nt < 2; nt++) {
        int n = nh + nt * 16 + lm;
        int phys = ((ks * 4 + q) ^ (n & 7)) * 16;
        const unsigned char* p = smem + 32768 + n * 256 + phys;
        bh[nt] = *(const bfrag*)p;
        bl[nt] = *(const bfrag*)(p + 128);
      }
#pragma unroll
      for (int mt = 0; mt < 4; mt++)
#pragma unroll
        for (int nt = 0; nt < 2; nt++) {
          acc[mt][nt] = __builtin_amdgcn_mfma_f32_16x16x32_bf16(ah[mt], bh[nt], acc[mt][nt], 0, 0, 0);
          acc[mt][nt] = __builtin_amdgcn_mfma_f32_16x16x32_bf16(ah[mt], bl[nt], acc[mt][nt], 0, 0, 0);
          acc[mt][nt] = __builtin_amdgcn_mfma_f32_16x16x32_bf16(al[mt], bh[nt], acc[mt][nt], 0, 0, 0);
        }
    }
  }
  if (EPI == 0) {
    // write conv2-input image: [g][cich 8][gy 32][gx 32] 128-B entries,
    // slot = chunk ^ ((gx+1)&7) (entry coord sx = gx+1 in consumer LDS).
    unsigned char* Yimg = (unsigned char*)out0;
    int g = zb;
#pragma unroll
    for (int mt = 0; mt < 4; mt++) {
      int mb = m0 + mh + mt * 16 + q * 4;
      int ch = mb >> 5, chunk = (mb >> 3) & 3, e2 = (mb & 7) * 2;
#pragma unroll
      for (int nt = 0; nt < 2; nt++) {
        int px = n0 + nh + nt * 16 + lm;
        int gy = px >> 5, gx = px & 31;
        int slot = chunk ^ ((gx + 1) & 7);
        size_t base = ((size_t)((g * 8 + ch) * 32 + gy)) * 4096 + gx * 128 + slot * 16 + e2;
        unsigned short hh[4], ll[4];
#pragma unroll
        for (int r = 0; r < 4; r++) {
          float v = acc[mt][nt][r] + p0[mb + r];
          hh[r] = bf16_rn(v);
          ll[r] = bf16_rn(v - __uint_as_float((unsigned)hh[r] << 16));
        }
        *(ushort4*)(Yimg + base) = make_ushort4(hh[0], hh[1], hh[2], hh[3]);
        *(ushort4*)(Yimg + (base ^ 64)) = make_ushort4(ll[0], ll[1], ll[2], ll[3]);
      }
    }
  } else if (EPI == 1) {
    float* S = (float*)out0 + (size_t)kh * 2097152;
    const float* stats = p0;
    const float* rowsum = p1;
    const float* gamma = p2;
    const float* bnb = p3;
    float a2v[2], t2v[2], r2v[2];
#pragma unroll
    for (int nt = 0; nt < 2; nt++) {
      int d = n0 + nh + nt * 16 + lm;
      float mu = stats[512 + d] * (1.f / 8192.f);
      float var = stats[1536 + d] * (1.f / 8192.f) - mu * mu;
      float a = gamma[d] * rsqrtf(var + 1e-5f);
      a2v[nt] = a;
      t2v[nt] = bnb[d] - mu * a;
      r2v[nt] = rowsum[(8 + zb) * 512 + d];
    }
#pragma unroll
    for (int mt = 0; mt < 4; mt++)
#pragma unroll
      for (int r = 0; r < 4; r++) {
        int cc = m0 + mh + mt * 16 + q * 4 + r;
        float mu = stats[cc] * (1.f / 8192.f);
        float var = stats[1024 + cc] * (1.f / 8192.f) - mu * mu;
        float a1 = gamma[cc] * rsqrtf(var + 1e-5f);
        float t1 = bnb[cc] - mu * a1;
        float r1 = rowsum[zb * 512 + cc];
#pragma unroll
        for (int nt = 0; nt < 2; nt++) {
          int d = n0 + nh + nt * 16 + lm;
          float sc = a1 * a2v[nt] * acc[mt][nt][r];
          if (kh == 0)
            sc += a1 * t2v[nt] * r1 + t1 * a2v[nt] * r2v[nt] + 1024.f * t1 * t2v[nt];
          S[((size_t)(zb * 512 + cc)) * 512 + d] = sc;
        }
      }
  } else {
    float* O = (float*)out0;
    float sc = p0[0];
#pragma unroll
    for (int mt = 0; mt < 4; mt++)
#pragma unroll
      for (int r = 0; r < 4; r++) {
        int cc = m0 + mh + mt * 16 + q * 4 + r;
#pragma unroll
        for (int nt = 0; nt < 2; nt++) {
          int n = n0 + nh + nt * 16 + lm;
          O[((size_t)(zb * 512 + cc)) * 1024 + n] = sc * acc[mt][nt][r];
        }
      }
  }
}

// conv2 3x3 SAME 256->512 split-bf16 MFMA (round-3 core, all staging via DMA).
// Input: Y1 conv-input image (4 KB strips per (g,cich,gy)); pads + out-of-range
// halo strips zeroed once in LDS, DMA fills interiors each ci-chunk.
__global__ __launch_bounds__(256, 2) void conv3x3_mfma(
    const unsigned char* __restrict__ Yimg, const unsigned short* __restrict__ w2s,
    const float* __restrict__ b2, unsigned char* __restrict__ Fimg,
    float* __restrict__ stats, float* __restrict__ rowsum) {
  __shared__ __attribute__((aligned(16))) unsigned char smem[75264];
  const int WOFF = 26112;  // input 204*128 B, then 384*128 B weights
  int t = threadIdx.x;
  int g = blockIdx.z;
  int panel = blockIdx.y;
  int co_base = panel * 128;
  int y0 = blockIdx.x * 4;
  int w = t >> 6, lane = t & 63;
  int lm = lane & 15, q = lane >> 4;
  int co_half = (w & 1) * 64, px_half = (w >> 1) * 64;
  int px_l[4], row_l[4], x_l[4];
#pragma unroll
  for (int i = 0; i < 4; i++) {
    px_l[i] = px_half + i * 16 + lm;
    row_l[i] = px_l[i] >> 5;
    x_l[i] = px_l[i] & 31;
  }
  // zero the whole input region once (pads + invalid halo strips stay zero)
  for (int u = t; u < 1632; u += 256)
    *(uint4*)(smem + u * 16) = make_uint4(0u, 0u, 0u, 0u);
  const unsigned char* wgbase =
      (const unsigned char*)w2s + (size_t)panel * 8 * 3 * 49152 + w * 12288 + lane * 16;
  const unsigned char* ldsw = smem + WOFF + w * 12288;
  facc acc[4][4] = {};  // [cotile][pxtile]
  for (int chunk = 0; chunk < 8; chunk++) {
    for (int dy = 0; dy < 3; dy++) {
      __syncthreads();
      {
        const unsigned char* gsrc = wgbase + (size_t)(chunk * 3 + dy) * 49152;
#pragma unroll
        for (int j = 0; j < 12; j++) dma16(gsrc + j * 1024, ldsw + j * 1024);
      }
      if (dy == 0) {
        // 6 strips x 4 KB; wave w handles ids w*6..w*6+5
#pragma unroll
        for (int j = 0; j < 6; j++) {
          int id = w * 6 + j;
          int strip = id >> 2, part = id & 3;
          int gy = y0 - 1 + strip;
          if ((unsigned)gy < 32u) {
            const unsigned char* src = Yimg +
                ((size_t)((g * 8 + chunk) * 32 + gy)) * 4096 + part * 1024 + lane * 16;
            dma16(src, smem + strip * 4352 + 128 + part * 1024);
          }
        }
      }
      __syncthreads();
#pragma unroll
      for (int dx = 0; dx < 3; dx++) {
        bfrag ah[4], al[4], bh[4], bl[4];
#pragma unroll
        for (int j = 0; j < 4; j++) {
          int cr = co_half + j * 16 + lm;
          const unsigned char* p = smem + WOFF + dx * 16384 + cr * 128;
          int ph = (q ^ (lm & 7)) * 16;
          ah[j] = *(const bfrag*)(p + ph);
          al[j] = *(const bfrag*)(p + (ph ^ 64));
        }
#pragma unroll
        for (int i = 0; i < 4; i++) {
          int xh = x_l[i] + dx;
          int entry = (row_l[i] + dy) * 34 + xh;
          const unsigned char* p = smem + entry * 128;
          int ph = (q ^ (xh & 7)) * 16;
          bh[i] = *(const bfrag*)(p + ph);
          bl[i] = *(const bfrag*)(p + (ph ^ 64));
        }
#pragma unroll
        for (int j = 0; j < 4; j++)
#pragma unroll
          for (int i = 0; i < 4; i++) {
            acc[j][i] = __builtin_amdgcn_mfma_f32_16x16x32_bf16(ah[j], bh[i], acc[j][i], 0, 0, 0);
            acc[j][i] = __builtin_amdgcn_mfma_f32_16x16x32_bf16(ah[j], bl[i], acc[j][i], 0, 0, 0);
            acc[j][i] = __builtin_amdgcn_mfma_f32_16x16x32_bf16(al[j], bh[i], acc[j][i], 0, 0, 0);
          }
      }
    }
  }
  // epilogue: +bias, LeakyReLU, write F image (scores operand) + stats/rowsums
  int grp = g >> 3;
  int px0 = blockIdx.x * 128;
#pragma unroll
  for (int j = 0; j < 4; j++) {
#pragma unroll
    for (int r = 0; r < 4; r++) {
      int co = co_base + co_half + j * 16 + q * 4 + r;
      int row = co & 127;
      float bb = b2[co];
      float s = 0.f, s2 = 0.f;
#pragma unroll
      for (int i = 0; i < 4; i++) {
        float v = acc[j][i][r] + bb;
        v = v > 0.f ? v : 0.01f * v;
        unsigned short h = bf16_rn(v);
        unsigned short l = bf16_rn(v - __uint_as_float((unsigned)h << 16));
        int px = px0 + px_l[i];
        int kc = px >> 6, ck = (px >> 3) & 7;
        int slot = ck ^ (row & 7);
        size_t byte = (((size_t)(g * 4 + panel) * 16 + kc) * 128 + row) * 256 +
                      slot * 16 + (px & 7) * 2;
        *(unsigned short*)(Fimg + byte) = h;
        *(unsigned short*)(Fimg + byte + 128) = l;
        s += v;
        s2 = fmaf(v, v, s2);
      }
#pragma unroll
      for (int d = 1; d <= 8; d <<= 1) {
        s += __shfl_xor(s, d);
        s2 += __shfl_xor(s2, d);
      }
      if (lm == 0) {
        atomicAdd(&stats[grp * 512 + co], s);
        atomicAdd(&stats[1024 + grp * 512 + co], s2);
        atomicAdd(&rowsum[g * 512 + co], s);
      }
    }
  }
}

// Row softmax over 512 (S0+S1 partials); writes att as pre-swizzled image.
__global__ __launch_bounds__(256) void softmax_rows(const float* __restrict__ S,
                                                    unsigned char* __restrict__ attimg) {
  int rowg = blockIdx.x;  // 0..4095
  int z = rowg >> 9, c = rowg & 511;
  const float* p = S + (size_t)rowg * 512;
  const float* p1 = p + 2097152;
  int t = threadIdx.x;
  float2 va = *(const float2*)(p + 2 * t);
  float2 vb = *(const float2*)(p1 + 2 * t);
  float vx = va.x + vb.x, vy = va.y + vb.y;
  float mx = fmaxf(vx, vy);
#pragma unroll
  for (int d = 32; d >= 1; d >>= 1) mx = fmaxf(mx, __shfl_xor(mx, d));
  __shared__ float sred[8];
  int wave = t >> 6, lane = t & 63;
  if (lane == 0) sred[wave] = mx;
  __syncthreads();
  float m4 = fmaxf(fmaxf(sred[0], sred[1]), fmaxf(sred[2], sred[3]));
  float ex = expf(vx - m4), ey = expf(vy - m4);
  float s = ex + ey;
#pragma unroll
  for (int d = 32; d >= 1; d >>= 1) s += __shfl_xor(s, d);
  if (lane == 0) sred[4 + wave] = s;
  __syncthreads();
  float inv = 1.f / (sred[4] + sred[5] + sred[6] + sred[7]);
  float px_ = ex * inv, py_ = ey * inv;
  unsigned short h0 = bf16_rn(px_), h1 = bf16_rn(py_);
  unsigned short l0 = bf16_rn(px_ - __uint_as_float((unsigned)h0 << 16));
  unsigned short l1 = bf16_rn(py_ - __uint_as_float((unsigned)h1 << 16));
  int rowl = c & 127, panel = c >> 7;
  int d0 = 2 * t;
  int kc = d0 >> 6, ck = (d0 >> 3) & 7;
  int slot = ck ^ (rowl & 7);
  size_t byte = (((size_t)(z * 4 + panel) * 8 + kc) * 128 + rowl) * 256 +
                slot * 16 + (d0 & 7) * 2;
  *(ushort2*)(attimg + byte) = make_ushort2(h0, h1);
  *(ushort2*)(attimg + byte + 128) = make_ushort2(l0, l1);
}

extern "C" void kernel_launch(void* const* d_in, const int* in_sizes, int n_in,
                              void* d_out, int out_size, void* d_ws, size_t ws_size,
                              hipStream_t stream) {
  const float* x = (const float*)d_in[0];
  const float* x1 = (const float*)d_in[1];
  const float* x2 = (const float*)d_in[2];
  const float* w1 = (const float*)d_in[3];
  const float* b1 = (const float*)d_in[4];
  const float* w2 = (const float*)d_in[5];
  const float* b2 = (const float*)d_in[6];
  const float* gamma = (const float*)d_in[7];
  const float* bnb = (const float*)d_in[8];
  const float* beta = (const float*)d_in[9];
  float* out = (float*)d_out;
  unsigned char* wsb = (unsigned char*)d_ws;

  unsigned char* x12timg = wsb;                    // 33,554,432 B (-> F image)
  unsigned char* Fimg = wsb;
  unsigned char* xtimg = wsb;                      // 16,777,216 B (after scores)
  unsigned char* attimg = wsb + 16777216;          // 8,388,608 B (after scores)
  unsigned char* Yimg = wsb + 33554432;            // 16,777,216 B (-> S0/S1)
  float* S = (float*)(wsb + 33554432);             // S0; S1 at +2,097,152 fl
  unsigned short* w2s = (unsigned short*)(wsb + 50331648);
  float* stats = (float*)(wsb + 55050240);         // 2048 fl
  float* rowsum = (float*)(wsb + 55058432);        // 8192 fl

  // prologue: x12t image + w2s image + stats zero
  prologue<<<8704, 256, 0, stream>>>(x1, x2, w2, x12timg, w2s, stats);
  // conv1: +b1, emit conv2-input image
  gemm_nt<512, 0, 1, 0><<<dim3(16, 2, 16), 256, 0, stream>>>(
      w1, 0LL, 0, x12timg, 2097152LL, 8, Yimg, b1, nullptr, nullptr, nullptr);
  // conv2 + bias + LeakyReLU -> F image + stats + rowsums
  conv3x3_mfma<<<dim3(8, 4, 16), 256, 0, stream>>>(
      Yimg, w2s, b2, Fimg, stats, rowsum);
  // scores (K-split x2) with BN folded -> S0, S1
  gemm_nt<512, 1, 0, 1><<<dim3(8, 4, 16), 256, 0, stream>>>(
      Fimg, 2097152LL, 16, Fimg + (size_t)8 * 2097152, 2097152LL, 16,
      S, stats, rowsum, gamma, bnb);
  // x -> xt image (F dead; overwrites RF front)
  transpose_split_x<<<dim3(32, 16, 8), 256, 0, stream>>>(x, xtimg);
  // softmax (S0+S1) -> att image
  softmax_rows<<<4096, 256, 0, stream>>>(S, attimg);
  // out: O[c][px] = beta * sum_d att*xt
  gemm_nt<512, 2, 0, 0><<<dim3(16, 4, 8), 256, 0, stream>>>(
      attimg, 1048576LL, 8, xtimg, 2097152LL, 8, out, beta, nullptr, nullptr, nullptr);
}